// Round 4
// baseline (52.658 us; speedup 1.0000x reference)
//
#include <hip/hip_runtime.h>
#include <math.h>

#define NPART 8
#define NN    128   // neighbors per batch
#define WPB   4     // waves per block
#define BPW   4     // batches per wave (pipelined)

// One WAVE processes BPW consecutive batches with register double-buffering:
// batch i+1's 8x float4 loads are issued BEFORE computing batch i, keeping
// 8KB in flight under every compute phase. 1024 blocks x 4 waves = 4096
// waves -> single occupancy round, no block barriers anywhere (per-wave
// private LDS bins, wave_barrier only = codegen fence, zero HW cost).
__global__ __launch_bounds__(256) void sc_kernel(
    const float* __restrict__ nei,   // (B, 128, 8, 2) f32
    const float* __restrict__ W,     // (3, 128) f32
    const float* __restrict__ bce,   // (128,) f32
    float* __restrict__ fsc,         // (B, 8, 128) f32
    float* __restrict__ scout,       // (B, 8, 3) f32
    int Btot)
{
    const int tid  = threadIdx.x;
    const int lane = tid & 63;
    const int wv   = tid >> 6;
    const int base = (blockIdx.x * WPB + wv) * BPW;

    __shared__ float s_sum[WPB][NPART * 3];
    __shared__ float s_cnt[WPB][NPART];
    __shared__ float s_sc[WPB][NPART * 3];

    // Epilogue weights: lane -> output columns 4*(lane&31) .. +3 (once/wave).
    const int c0i = 4 * (lane & 31);
    float4 wr0 = *reinterpret_cast<const float4*>(W + 0 * NN + c0i);
    float4 wr1 = *reinterpret_cast<const float4*>(W + 1 * NN + c0i);
    float4 wr2 = *reinterpret_cast<const float4*>(W + 2 * NN + c0i);
    float4 bb  = *reinterpret_cast<const float4*>(bce + c0i);

    const float TWOPI = 6.2831853071795864769f;
    const float STEP  = (float)(6.283185307179586 / 8.0);

    const float4* nei4 = reinterpret_cast<const float4*>(nei);

    float4 buf[2][8];   // double buffer; always indexed with unroll-constant i&1

    // ---- prologue: issue batch base's loads ----
    if (base < Btot) {
        const float4* s = nei4 + (size_t)base * (NN * 4);
        #pragma unroll
        for (int k = 0; k < 4; ++k) buf[0][k]     = s[lane * 4 + k];
        #pragma unroll
        for (int k = 0; k < 4; ++k) buf[0][4 + k] = s[256 + lane * 4 + k];
    }

    #pragma unroll
    for (int i = 0; i < BPW; ++i) {
        const int b = base + i;
        if (b < Btot) {
            // -- prefetch next batch into the other buffer (stays in flight) --
            if (i + 1 < BPW && b + 1 < Btot) {
                const float4* s = nei4 + (size_t)(b + 1) * (NN * 4);
                #pragma unroll
                for (int k = 0; k < 4; ++k) buf[(i + 1) & 1][k]     = s[lane * 4 + k];
                #pragma unroll
                for (int k = 0; k < 4; ++k) buf[(i + 1) & 1][4 + k] = s[256 + lane * 4 + k];
            }

            // -- reset this wave's bins --
            if (lane < NPART * 3) s_sum[wv][lane] = 0.0f;
            if (lane < NPART)     s_cnt[wv][lane] = 0.0f;
            __builtin_amdgcn_wave_barrier();

            // -- features for neighbors lane, lane+64 --
            #pragma unroll
            for (int h = 0; h < 2; ++h) {
                float4 a = buf[i & 1][h * 4 + 0];
                float4 c = buf[i & 1][h * 4 + 1];
                float4 d = buf[i & 1][h * 4 + 2];
                float4 e = buf[i & 1][h * 4 + 3];

                float total = (((a.x + a.y) + (a.z + a.w)) + ((c.x + c.y) + (c.z + c.w)))
                            + (((d.x + d.y) + (d.z + d.w)) + ((e.x + e.y) + (e.z + e.w)));

                float px = e.z, py = e.w;            // last position (t7)
                float vx = px - a.x, vy = py - a.y;  // last - first
                float fvel  = sqrtf(vx * vx + vy * vy);
                float fdist = sqrtf(px * px + py * py);

                float fdir = atan2f(px, py);
                if (fdir < 0.0f) fdir += TWOPI;

                int idx = (int)(fdir / STEP);

                if (total != 0.0f && idx >= 0 && idx < NPART) {
                    atomicAdd(&s_sum[wv][idx * 3 + 0], fvel);
                    atomicAdd(&s_sum[wv][idx * 3 + 1], fdist);
                    atomicAdd(&s_sum[wv][idx * 3 + 2], fdir);
                    atomicAdd(&s_cnt[wv][idx], 1.0f);
                }
            }
            __builtin_amdgcn_wave_barrier();

            // -- finalize social_circle, write output 1 --
            if (lane < NPART * 3) {
                float v = s_sum[wv][lane] / (s_cnt[wv][lane / 3] + 0.0001f);
                s_sc[wv][lane] = v;
                scout[(size_t)b * (NPART * 3) + lane] = v;
            }
            __builtin_amdgcn_wave_barrier();

            // -- epilogue: f_sc = relu(sc @ W + b); float4 stores --
            float* o = fsc + (size_t)b * NPART * NN;
            #pragma unroll
            for (int s = 0; s < 4; ++s) {
                int p = 2 * s + (lane >> 5);
                float sv = s_sc[wv][p * 3 + 0];   // 2-address broadcast: free
                float sd = s_sc[wv][p * 3 + 1];
                float sr = s_sc[wv][p * 3 + 2];
                float4 acc;
                acc.x = fmaxf(fmaf(sv, wr0.x, fmaf(sd, wr1.x, fmaf(sr, wr2.x, bb.x))), 0.0f);
                acc.y = fmaxf(fmaf(sv, wr0.y, fmaf(sd, wr1.y, fmaf(sr, wr2.y, bb.y))), 0.0f);
                acc.z = fmaxf(fmaf(sv, wr0.z, fmaf(sd, wr1.z, fmaf(sr, wr2.z, bb.z))), 0.0f);
                acc.w = fmaxf(fmaf(sv, wr0.w, fmaf(sd, wr1.w, fmaf(sr, wr2.w, bb.w))), 0.0f);
                *reinterpret_cast<float4*>(o + p * NN + c0i) = acc;
            }
        }
    }
}

extern "C" void kernel_launch(void* const* d_in, const int* in_sizes, int n_in,
                              void* d_out, int out_size, void* d_ws, size_t ws_size,
                              hipStream_t stream) {
    // inputs: 0=trajs (UNUSED by reference), 1=nei_trajs, 2=W_ce, 3=b_ce
    const float* nei = (const float*)d_in[1];
    const float* W   = (const float*)d_in[2];
    const float* bce = (const float*)d_in[3];

    const int Btot = in_sizes[1] / (NN * 8 * 2);   // 16384

    // outputs concatenated: f_sc (B,8,128) then social_circle (B,8,3)
    float* fsc   = (float*)d_out;
    float* scout = fsc + (size_t)Btot * NPART * NN;

    const int nblk = (Btot + WPB * BPW - 1) / (WPB * BPW);
    sc_kernel<<<nblk, 256, 0, stream>>>(nei, W, bce, fsc, scout, Btot);
}

// Round 6
// 51.845 us; speedup vs baseline: 1.0157x; 1.0157x over previous
//
#include <hip/hip_runtime.h>
#include <math.h>

#define NPART 8
#define NN    128   // neighbors per batch

typedef float f32x4 __attribute__((ext_vector_type(4)));

// One WAVE per batch element (R3 geometry — best so far). 256-thread blocks
// = 4 independent waves, per-wave private LDS bins, no __syncthreads.
// Lane l handles neighbors l and l+64 (8x float4 nontemporal loads).
// All output stores are nontemporal: outputs are never re-read, and the
// input is read-once -> keep BOTH streams out of L2 so neither evicts the
// other (write-allocate thrash is the theory for the 1.8 TB/s plateau).
__global__ __launch_bounds__(256) void sc_kernel(
    const float* __restrict__ nei,   // (B, 128, 8, 2) f32
    const float* __restrict__ W,     // (3, 128) f32
    const float* __restrict__ bce,   // (128,) f32
    float* __restrict__ fsc,         // (B, 8, 128) f32
    float* __restrict__ scout,       // (B, 8, 3) f32
    int Btot)
{
    const int tid  = threadIdx.x;
    const int lane = tid & 63;
    const int wv   = tid >> 6;
    const int b    = blockIdx.x * 4 + wv;
    if (b >= Btot) return;

    __shared__ float s_sum[4][NPART * 3];
    __shared__ float s_cnt[4][NPART];
    __shared__ float s_sc[4][NPART * 3];

    // ---- issue all 8 input loads first (nontemporal, read-once) ----
    const f32x4* src = reinterpret_cast<const f32x4*>(nei) + (size_t)b * (NN * 4);
    f32x4 a0 = __builtin_nontemporal_load(src + lane * 4 + 0);
    f32x4 c0 = __builtin_nontemporal_load(src + lane * 4 + 1);
    f32x4 d0 = __builtin_nontemporal_load(src + lane * 4 + 2);
    f32x4 e0 = __builtin_nontemporal_load(src + lane * 4 + 3);
    f32x4 a1 = __builtin_nontemporal_load(src + 256 + lane * 4 + 0);
    f32x4 c1 = __builtin_nontemporal_load(src + 256 + lane * 4 + 1);
    f32x4 d1 = __builtin_nontemporal_load(src + 256 + lane * 4 + 2);
    f32x4 e1 = __builtin_nontemporal_load(src + 256 + lane * 4 + 3);

    // Epilogue weights: lane -> output columns 4*(lane&31)..+3 (L2-hot, reused).
    const int c0i = 4 * (lane & 31);
    f32x4 wr0 = *reinterpret_cast<const f32x4*>(W + 0 * NN + c0i);
    f32x4 wr1 = *reinterpret_cast<const f32x4*>(W + 1 * NN + c0i);
    f32x4 wr2 = *reinterpret_cast<const f32x4*>(W + 2 * NN + c0i);
    f32x4 bb  = *reinterpret_cast<const f32x4*>(bce + c0i);

    // per-wave LDS bin init (same wave consumes -> no HW barrier needed)
    if (lane < NPART * 3) s_sum[wv][lane] = 0.0f;
    if (lane < NPART)     s_cnt[wv][lane] = 0.0f;
    __builtin_amdgcn_wave_barrier();

    const float TWOPI = 6.2831853071795864769f;
    const float STEP  = (float)(6.283185307179586 / 8.0);

    #pragma unroll
    for (int h = 0; h < 2; ++h) {
        f32x4 a = h ? a1 : a0;
        f32x4 c = h ? c1 : c0;
        f32x4 d = h ? d1 : d0;
        f32x4 e = h ? e1 : e0;

        float total = (((a.x + a.y) + (a.z + a.w)) + ((c.x + c.y) + (c.z + c.w)))
                    + (((d.x + d.y) + (d.z + d.w)) + ((e.x + e.y) + (e.z + e.w)));

        float px = e.z, py = e.w;            // last position (t7)
        float vx = px - a.x, vy = py - a.y;  // last - first
        float fvel  = sqrtf(vx * vx + vy * vy);
        float fdist = sqrtf(px * px + py * py);

        float fdir = atan2f(px, py);
        if (fdir < 0.0f) fdir += TWOPI;

        int idx = (int)(fdir / STEP);

        if (total != 0.0f && idx >= 0 && idx < NPART) {
            atomicAdd(&s_sum[wv][idx * 3 + 0], fvel);
            atomicAdd(&s_sum[wv][idx * 3 + 1], fdist);
            atomicAdd(&s_sum[wv][idx * 3 + 2], fdir);
            atomicAdd(&s_cnt[wv][idx], 1.0f);
        }
    }
    __builtin_amdgcn_wave_barrier();

    // ---- finalize social_circle (lanes 0..23), write output 1 ----
    if (lane < NPART * 3) {
        float v = s_sum[wv][lane] / (s_cnt[wv][lane / 3] + 0.0001f);
        s_sc[wv][lane] = v;
        __builtin_nontemporal_store(v, scout + (size_t)b * (NPART * 3) + lane);
    }
    __builtin_amdgcn_wave_barrier();

    // ---- epilogue: f_sc = relu(sc @ W + b); 4x float4 nt stores ----
    float* o = fsc + (size_t)b * NPART * NN;
    #pragma unroll
    for (int s = 0; s < 4; ++s) {
        int p = 2 * s + (lane >> 5);
        float sv = s_sc[wv][p * 3 + 0];   // 2-address broadcast: conflict-free
        float sd = s_sc[wv][p * 3 + 1];
        float sr = s_sc[wv][p * 3 + 2];
        f32x4 acc;
        acc.x = fmaxf(fmaf(sv, wr0.x, fmaf(sd, wr1.x, fmaf(sr, wr2.x, bb.x))), 0.0f);
        acc.y = fmaxf(fmaf(sv, wr0.y, fmaf(sd, wr1.y, fmaf(sr, wr2.y, bb.y))), 0.0f);
        acc.z = fmaxf(fmaf(sv, wr0.z, fmaf(sd, wr1.z, fmaf(sr, wr2.z, bb.z))), 0.0f);
        acc.w = fmaxf(fmaf(sv, wr0.w, fmaf(sd, wr1.w, fmaf(sr, wr2.w, bb.w))), 0.0f);
        __builtin_nontemporal_store(acc, reinterpret_cast<f32x4*>(o + p * NN + c0i));
    }
}

extern "C" void kernel_launch(void* const* d_in, const int* in_sizes, int n_in,
                              void* d_out, int out_size, void* d_ws, size_t ws_size,
                              hipStream_t stream) {
    // inputs: 0=trajs (UNUSED by reference), 1=nei_trajs, 2=W_ce, 3=b_ce
    const float* nei = (const float*)d_in[1];
    const float* W   = (const float*)d_in[2];
    const float* bce = (const float*)d_in[3];

    const int Btot = in_sizes[1] / (NN * 8 * 2);   // 16384

    // outputs concatenated: f_sc (B,8,128) then social_circle (B,8,3)
    float* fsc   = (float*)d_out;
    float* scout = fsc + (size_t)Btot * NPART * NN;

    const int nblk = (Btot + 3) / 4;
    sc_kernel<<<nblk, 256, 0, stream>>>(nei, W, bce, fsc, scout, Btot);
}